// Round 1
// baseline (415.885 us; speedup 1.0000x reference)
//
#include <hip/hip_runtime.h>

// TimeFeatureEmbedding: y[b,t,d] = sum_e x[b,t,e]*W[d,e] + b[d], broadcast
// to [B,T,S,D]. D=512, d_inp=4, S=64. Output 402.65 MB fp32 -> pure
// store-BW-bound. Floor = 402.65MB / 6.35 TB/s (fillBuffer-measured write
// ceiling) ~= 63 us.
//
// R2 theory: dur_us (404) = harness poison fill (~253us, fixed) + kernel
// (~151us = 2.7 TB/s). The flat-pattern kernel's in-loop global load
// x4[bt] shares the in-order vmcnt counter with the BW-saturated stores:
// waiting for the load drains all older stores -> wave iteration rate
// chained to store-RETIRE latency. Fix: stage the 48 x-values each block
// needs (768 B) into LDS up front; main loop = ds_read (lgkmcnt) + fma +
// store (vmcnt, never waited) -> store stream identical to fillBuffer's.

#define D_MODEL 512
#define D_INP   4

// Flat grid-stride store kernel with LDS-staged x.
// Preconditions (checked at launch): stride % (S*128) == 0 so (s,d4) and
// btStep are invariant; blockDim divides S*128 so bt0 is block-uniform;
// N4 % stride == 0 so all threads run exactly niter iterations; niter<=64.
__global__ __launch_bounds__(256) void tfe_flat_lds(
    const float4* __restrict__ x4,   // [BT]   x rows as float4 (d_inp=4)
    const float4* __restrict__ W4,   // [512]  each W row is one float4
    const float4* __restrict__ b4,   // [128]  bias as float4
    float4* __restrict__ out4,       // flat output as float4
    int btShift, int niter)
{
    __shared__ float4 xs[64];        // niter <= 64 (=48 for S=64 shape)

    const size_t stride = (size_t)gridDim.x * blockDim.x;
    const size_t f = (size_t)blockIdx.x * blockDim.x + threadIdx.x;
    const int d4 = (int)(f & 127);                      // stride%128==0 -> const
    const int btStep = (int)(stride >> btShift);        // 64
    const int bt0 = (int)(((size_t)blockIdx.x * blockDim.x) >> btShift); // block-uniform

    // Stage this block's x values: thread i (< niter) fetches x4[bt0+i*btStep].
    if ((int)threadIdx.x < niter)
        xs[threadIdx.x] = x4[bt0 + btStep * (int)threadIdx.x];

    const float4 w0 = W4[4 * d4 + 0];
    const float4 w1 = W4[4 * d4 + 1];
    const float4 w2 = W4[4 * d4 + 2];
    const float4 w3 = W4[4 * d4 + 3];
    const float4 bv = b4[d4];
    __syncthreads();

    // Main loop: no global loads -> no vmcnt waits; stores stream at BW.
    float4* o = out4 + f;
    #pragma unroll 4
    for (int i = 0; i < niter; ++i, o += stride) {
        const float4 xv = xs[i];                        // LDS broadcast, conflict-free
        float4 y;
        y.x = fmaf(xv.x, w0.x, fmaf(xv.y, w0.y, fmaf(xv.z, w0.z, fmaf(xv.w, w0.w, bv.x))));
        y.y = fmaf(xv.x, w1.x, fmaf(xv.y, w1.y, fmaf(xv.z, w1.z, fmaf(xv.w, w1.w, bv.y))));
        y.z = fmaf(xv.x, w2.x, fmaf(xv.y, w2.y, fmaf(xv.z, w2.z, fmaf(xv.w, w2.w, bv.z))));
        y.w = fmaf(xv.x, w3.x, fmaf(xv.y, w3.y, fmaf(xv.z, w3.z, fmaf(xv.w, w3.w, bv.w))));
        *o = y;                                         // 1KB/wave contiguous
    }
}

// R2 fallback (previous best): flat grid-stride with in-loop x load.
__global__ __launch_bounds__(256) void tfe_flat(
    const float4* __restrict__ x4, const float4* __restrict__ W4,
    const float4* __restrict__ b4, float4* __restrict__ out4,
    size_t N4, int btShift)
{
    const size_t stride = (size_t)gridDim.x * blockDim.x;
    size_t f = (size_t)blockIdx.x * blockDim.x + threadIdx.x;
    const int d4 = (int)(f & 127);

    const float4 w0 = W4[4 * d4 + 0];
    const float4 w1 = W4[4 * d4 + 1];
    const float4 w2 = W4[4 * d4 + 2];
    const float4 w3 = W4[4 * d4 + 3];
    const float4 bv = b4[d4];

    for (; f < N4; f += stride) {
        const int bt = (int)(f >> btShift);
        const float4 xv = x4[bt];
        float4 y;
        y.x = fmaf(xv.x, w0.x, fmaf(xv.y, w0.y, fmaf(xv.z, w0.z, fmaf(xv.w, w0.w, bv.x))));
        y.y = fmaf(xv.x, w1.x, fmaf(xv.y, w1.y, fmaf(xv.z, w1.z, fmaf(xv.w, w1.w, bv.y))));
        y.z = fmaf(xv.x, w2.x, fmaf(xv.y, w2.y, fmaf(xv.z, w2.z, fmaf(xv.w, w2.w, bv.z))));
        y.w = fmaf(xv.x, w3.x, fmaf(xv.y, w3.y, fmaf(xv.z, w3.z, fmaf(xv.w, w3.w, bv.w))));
        out4[f] = y;
    }
}

// Fallback for non-pow2 S: block-per-(b,t) kernel.
__global__ __launch_bounds__(256) void tfe_embed_bcast(
    const float* __restrict__ x, const float* __restrict__ W,
    const float* __restrict__ bias, float* __restrict__ out, int S)
{
    const int bt = blockIdx.x;
    const int tid = threadIdx.x;
    const int d4 = tid & 127;
    const int shalf = tid >> 7;
    const float4 xv = ((const float4*)x)[bt];
    const float4* Wv = (const float4*)W;
    const float4 w0 = Wv[4 * d4 + 0];
    const float4 w1 = Wv[4 * d4 + 1];
    const float4 w2 = Wv[4 * d4 + 2];
    const float4 w3 = Wv[4 * d4 + 3];
    const float4 bv = ((const float4*)bias)[d4];
    float4 y;
    y.x = fmaf(xv.x, w0.x, fmaf(xv.y, w0.y, fmaf(xv.z, w0.z, fmaf(xv.w, w0.w, bv.x))));
    y.y = fmaf(xv.x, w1.x, fmaf(xv.y, w1.y, fmaf(xv.z, w1.z, fmaf(xv.w, w1.w, bv.y))));
    y.z = fmaf(xv.x, w2.x, fmaf(xv.y, w2.y, fmaf(xv.z, w2.z, fmaf(xv.w, w2.w, bv.z))));
    y.w = fmaf(xv.x, w3.x, fmaf(xv.y, w3.y, fmaf(xv.z, w3.z, fmaf(xv.w, w3.w, bv.w))));
    float4* orow = (float4*)out + (size_t)bt * (size_t)S * 128;
    for (int si = shalf; si < S; si += 2)
        orow[(size_t)si * 128 + d4] = y;
}

extern "C" void kernel_launch(void* const* d_in, const int* in_sizes, int n_in,
                              void* d_out, int out_size, void* d_ws, size_t ws_size,
                              hipStream_t stream) {
    const float* x    = (const float*)d_in[0];   // [B,T,4] fp32
    const float* W    = (const float*)d_in[2];   // [512,4] fp32
    const float* bias = (const float*)d_in[3];   // [512]   fp32
    float* out        = (float*)d_out;

    const int BT = in_sizes[0] / D_INP;               // 3072 (sizes in elements)
    const int S  = out_size / (BT * D_MODEL);         // 64
    const size_t N4 = (size_t)out_size / 4;           // float4 count

    if ((S & (S - 1)) == 0) {
        // btShift = log2(S * 128): S=64 -> 13
        int btShift = 0, v = S * (D_MODEL / 4);
        while ((1 << (btShift + 1)) <= v) ++btShift;

        const int G = 2048, B = 256;                  // 8 blocks/CU resident
        const size_t stride = (size_t)G * B;          // 524288 float4
        const size_t row = (size_t)S * (D_MODEL / 4); // float4 per bt (8192)
        const size_t niter = (stride && N4 >= stride) ? N4 / stride : 0;

        if (niter >= 1 && niter <= 64 &&
            (N4 % stride) == 0 &&                     // all threads run niter iters
            (stride % row) == 0 &&                    // (s,d4) invariant, btStep exact
            (row % (size_t)B) == 0) {                 // bt0 block-uniform
            tfe_flat_lds<<<G, B, 0, stream>>>(
                (const float4*)x, (const float4*)W, (const float4*)bias,
                (float4*)out, btShift, (int)niter);
        } else {
            tfe_flat<<<G, B, 0, stream>>>(
                (const float4*)x, (const float4*)W, (const float4*)bias,
                (float4*)out, N4, btShift);
        }
    } else {
        tfe_embed_bcast<<<BT, 256, 0, stream>>>(x, W, bias, out, S);
    }
}

// Round 3
// 409.499 us; speedup vs baseline: 1.0156x; 1.0156x over previous
//
#include <hip/hip_runtime.h>

// TimeFeatureEmbedding: y[b,t,d] = sum_e x[b,t,e]*W[d,e] + b[d], broadcast
// to [B,T,S,D]. D=512, d_inp=4, S=64. Output 402.65 MB fp32 -> pure
// store-BW-bound. Floor = 402.65MB / 6.3 TB/s ~= 64 us (+ ~255 us fixed
// harness poison fill inside the timed region).
//
// R2 post-mortem: removing in-loop global loads (LDS-staged x) was NEUTRAL
// (kernel ~153 us both rounds, ~2.6 TB/s) -> limit is store backpressure,
// not loop-body waits. fillBuffer hits 6.2 TB/s on the same flat pattern.
// Remaining structural difference: store TYPE. Plain stores write-ALLOCATE
// in L2 (allocate + later evict = ~2x slice work/byte); rocclr's fill path
// streams. R3: __builtin_nontemporal_store ('nt' cache policy, no L2
// allocate). R3 compile fix: the builtin requires a NATIVE clang vector
// type, not HIP_vector_type float4 -> use ext_vector_type(4).

#define D_MODEL 512
#define D_INP   4

typedef float v4f __attribute__((ext_vector_type(4)));

__device__ __forceinline__ v4f tfe_row(const float4 xv, const float4 w0,
                                       const float4 w1, const float4 w2,
                                       const float4 w3, const float4 bv) {
    v4f y;
    y.x = fmaf(xv.x, w0.x, fmaf(xv.y, w0.y, fmaf(xv.z, w0.z, fmaf(xv.w, w0.w, bv.x))));
    y.y = fmaf(xv.x, w1.x, fmaf(xv.y, w1.y, fmaf(xv.z, w1.z, fmaf(xv.w, w1.w, bv.y))));
    y.z = fmaf(xv.x, w2.x, fmaf(xv.y, w2.y, fmaf(xv.z, w2.z, fmaf(xv.w, w2.w, bv.z))));
    y.w = fmaf(xv.x, w3.x, fmaf(xv.y, w3.y, fmaf(xv.z, w3.z, fmaf(xv.w, w3.w, bv.w))));
    return y;
}

// Flat grid-stride store kernel with LDS-staged x and nontemporal stores.
// Preconditions (checked at launch): stride % (S*128) == 0 so (s,d4) and
// btStep are invariant; blockDim divides S*128 so bt0 is block-uniform;
// N4 % stride == 0 so all threads run exactly niter iterations; niter<=64.
__global__ __launch_bounds__(256) void tfe_flat_lds_nt(
    const float4* __restrict__ x4,   // [BT]   x rows as float4 (d_inp=4)
    const float4* __restrict__ W4,   // [512]  each W row is one float4
    const float4* __restrict__ b4,   // [128]  bias as float4
    v4f* __restrict__ out4,          // flat output as native float4
    int btShift, int niter)
{
    __shared__ float4 xs[64];        // niter <= 64 (=48 for S=64 shape)

    const size_t stride = (size_t)gridDim.x * blockDim.x;
    const size_t f = (size_t)blockIdx.x * blockDim.x + threadIdx.x;
    const int d4 = (int)(f & 127);                      // stride%128==0 -> const
    const int btStep = (int)(stride >> btShift);        // 64
    const int bt0 = (int)(((size_t)blockIdx.x * blockDim.x) >> btShift); // block-uniform

    if ((int)threadIdx.x < niter)
        xs[threadIdx.x] = x4[bt0 + btStep * (int)threadIdx.x];

    const float4 w0 = W4[4 * d4 + 0];
    const float4 w1 = W4[4 * d4 + 1];
    const float4 w2 = W4[4 * d4 + 2];
    const float4 w3 = W4[4 * d4 + 3];
    const float4 bv = b4[d4];
    __syncthreads();

    v4f* o = out4 + f;
    #pragma unroll 4
    for (int i = 0; i < niter; ++i, o += stride) {
        const v4f y = tfe_row(xs[i], w0, w1, w2, w3, bv);
        __builtin_nontemporal_store(y, o);              // nt: no L2 allocate
    }
}

// Fallback: flat grid-stride with in-loop x load (any pow2 S shape).
__global__ __launch_bounds__(256) void tfe_flat(
    const float4* __restrict__ x4, const float4* __restrict__ W4,
    const float4* __restrict__ b4, v4f* __restrict__ out4,
    size_t N4, int btShift)
{
    const size_t stride = (size_t)gridDim.x * blockDim.x;
    size_t f = (size_t)blockIdx.x * blockDim.x + threadIdx.x;
    const int d4 = (int)(f & 127);

    const float4 w0 = W4[4 * d4 + 0];
    const float4 w1 = W4[4 * d4 + 1];
    const float4 w2 = W4[4 * d4 + 2];
    const float4 w3 = W4[4 * d4 + 3];
    const float4 bv = b4[d4];

    for (; f < N4; f += stride) {
        const int bt = (int)(f >> btShift);
        const v4f y = tfe_row(x4[bt], w0, w1, w2, w3, bv);
        __builtin_nontemporal_store(y, &out4[f]);
    }
}

// Fallback for non-pow2 S: block-per-(b,t) kernel.
__global__ __launch_bounds__(256) void tfe_embed_bcast(
    const float* __restrict__ x, const float* __restrict__ W,
    const float* __restrict__ bias, float* __restrict__ out, int S)
{
    const int bt = blockIdx.x;
    const int tid = threadIdx.x;
    const int d4 = tid & 127;
    const int shalf = tid >> 7;
    const float4 xv = ((const float4*)x)[bt];
    const float4* Wv = (const float4*)W;
    const float4 w0 = Wv[4 * d4 + 0];
    const float4 w1 = Wv[4 * d4 + 1];
    const float4 w2 = Wv[4 * d4 + 2];
    const float4 w3 = Wv[4 * d4 + 3];
    const float4 bv = ((const float4*)bias)[d4];
    const v4f y = tfe_row(xv, w0, w1, w2, w3, bv);
    v4f* orow = (v4f*)out + (size_t)bt * (size_t)S * 128;
    for (int si = shalf; si < S; si += 2)
        __builtin_nontemporal_store(y, &orow[(size_t)si * 128 + d4]);
}

extern "C" void kernel_launch(void* const* d_in, const int* in_sizes, int n_in,
                              void* d_out, int out_size, void* d_ws, size_t ws_size,
                              hipStream_t stream) {
    const float* x    = (const float*)d_in[0];   // [B,T,4] fp32
    const float* W    = (const float*)d_in[2];   // [512,4] fp32
    const float* bias = (const float*)d_in[3];   // [512]   fp32
    float* out        = (float*)d_out;

    const int BT = in_sizes[0] / D_INP;               // 3072 (sizes in elements)
    const int S  = out_size / (BT * D_MODEL);         // 64
    const size_t N4 = (size_t)out_size / 4;           // float4 count

    if ((S & (S - 1)) == 0) {
        // btShift = log2(S * 128): S=64 -> 13
        int btShift = 0, v = S * (D_MODEL / 4);
        while ((1 << (btShift + 1)) <= v) ++btShift;

        const int G = 2048, B = 256;                  // 8 blocks/CU, 32 waves/CU
        const size_t stride = (size_t)G * B;          // 524288 float4
        const size_t row = (size_t)S * (D_MODEL / 4); // float4 per bt (8192)
        const size_t niter = (stride && N4 >= stride) ? N4 / stride : 0;

        if (niter >= 1 && niter <= 64 &&
            (N4 % stride) == 0 &&                     // all threads run niter iters
            (stride % row) == 0 &&                    // (s,d4) invariant, btStep exact
            (row % (size_t)B) == 0) {                 // bt0 block-uniform
            tfe_flat_lds_nt<<<G, B, 0, stream>>>(
                (const float4*)x, (const float4*)W, (const float4*)bias,
                (v4f*)out, btShift, (int)niter);
        } else {
            tfe_flat<<<G, B, 0, stream>>>(
                (const float4*)x, (const float4*)W, (const float4*)bias,
                (v4f*)out, N4, btShift);
        }
    } else {
        tfe_embed_bcast<<<BT, 256, 0, stream>>>(x, W, bias, out, S);
    }
}

// Round 4
// 394.826 us; speedup vs baseline: 1.0533x; 1.0372x over previous
//
#include <hip/hip_runtime.h>

// TimeFeatureEmbedding: y[b,t,d] = sum_e x[b,t,e]*W[d,e] + b[d], broadcast
// to [B,T,S,D]. D=512, d_inp=4, S=64. Output 402.65 MB fp32 -> pure
// store-BW-bound. Floor = 402.65MB / 6.3 TB/s ~= 64 us (+ ~255 us fixed
// harness poison fill inside the timed region).
//
// Dead theories (all NEUTRAL, kernel ~151-155 us = 2.6 TB/s):
//   R1 in-loop global load vmcnt coupling (LDS staging: neutral)
//   R3 L2 write-allocate policy (nontemporal store: neutral)
// R4 theory: CONCURRENCY. fillBuffer rows show OccupancyPercent ~10% ->
// rocclr fills with a ~205-block grid (~3.3 waves/CU) and hits 6.3 TB/s;
// we ran 2048 blocks (32 waves/CU). Time-sliced waves desynchronize the
// flat write front -> each HBM bank sees many interleaved streams -> row
// thrash (~40% page-hit eff = 2.6/6.3). R4: grid 2048 -> 256 (1 block/CU,
// 4 waves/CU), flat pattern and loop body unchanged.

#define D_MODEL 512
#define D_INP   4

typedef float v4f __attribute__((ext_vector_type(4)));

__device__ __forceinline__ v4f tfe_row(const float4 xv, const float4 w0,
                                       const float4 w1, const float4 w2,
                                       const float4 w3, const float4 bv) {
    v4f y;
    y.x = fmaf(xv.x, w0.x, fmaf(xv.y, w0.y, fmaf(xv.z, w0.z, fmaf(xv.w, w0.w, bv.x))));
    y.y = fmaf(xv.x, w1.x, fmaf(xv.y, w1.y, fmaf(xv.z, w1.z, fmaf(xv.w, w1.w, bv.y))));
    y.z = fmaf(xv.x, w2.x, fmaf(xv.y, w2.y, fmaf(xv.z, w2.z, fmaf(xv.w, w2.w, bv.z))));
    y.w = fmaf(xv.x, w3.x, fmaf(xv.y, w3.y, fmaf(xv.z, w3.z, fmaf(xv.w, w3.w, bv.w))));
    return y;
}

// Flat grid-stride store kernel with LDS-staged x and nontemporal stores.
// Preconditions (checked at launch): stride % (S*128) == 0 so (s,d4) and
// btStep are invariant; blockDim divides S*128 so bt0 is block-uniform;
// N4 % stride == 0 so all threads run exactly niter iterations; niter<=1536.
__global__ __launch_bounds__(256) void tfe_flat_lds_nt(
    const float4* __restrict__ x4,   // [BT]   x rows as float4 (d_inp=4)
    const float4* __restrict__ W4,   // [512]  each W row is one float4
    const float4* __restrict__ b4,   // [128]  bias as float4
    v4f* __restrict__ out4,          // flat output as native float4
    int btShift, int niter)
{
    __shared__ float4 xs[1536];      // 24 KB; niter<=1536 (=384 for S=64,G=256)

    const size_t stride = (size_t)gridDim.x * blockDim.x;
    const size_t f = (size_t)blockIdx.x * blockDim.x + threadIdx.x;
    const int d4 = (int)(f & 127);                      // stride%128==0 -> const
    const int btStep = (int)(stride >> btShift);        // 8 at G=256
    const int bt0 = (int)(((size_t)blockIdx.x * blockDim.x) >> btShift); // block-uniform

    for (int j = (int)threadIdx.x; j < niter; j += (int)blockDim.x)
        xs[j] = x4[bt0 + btStep * j];

    const float4 w0 = W4[4 * d4 + 0];
    const float4 w1 = W4[4 * d4 + 1];
    const float4 w2 = W4[4 * d4 + 2];
    const float4 w3 = W4[4 * d4 + 3];
    const float4 bv = b4[d4];
    __syncthreads();

    v4f* o = out4 + f;
    #pragma unroll 4
    for (int i = 0; i < niter; ++i, o += stride) {
        const v4f y = tfe_row(xs[i], w0, w1, w2, w3, bv);
        __builtin_nontemporal_store(y, o);              // nt (neutral, harmless)
    }
}

// Fallback: flat grid-stride with in-loop x load (any pow2 S shape).
__global__ __launch_bounds__(256) void tfe_flat(
    const float4* __restrict__ x4, const float4* __restrict__ W4,
    const float4* __restrict__ b4, v4f* __restrict__ out4,
    size_t N4, int btShift)
{
    const size_t stride = (size_t)gridDim.x * blockDim.x;
    size_t f = (size_t)blockIdx.x * blockDim.x + threadIdx.x;
    const int d4 = (int)(f & 127);

    const float4 w0 = W4[4 * d4 + 0];
    const float4 w1 = W4[4 * d4 + 1];
    const float4 w2 = W4[4 * d4 + 2];
    const float4 w3 = W4[4 * d4 + 3];
    const float4 bv = b4[d4];

    for (; f < N4; f += stride) {
        const int bt = (int)(f >> btShift);
        const v4f y = tfe_row(x4[bt], w0, w1, w2, w3, bv);
        __builtin_nontemporal_store(y, &out4[f]);
    }
}

// Fallback for non-pow2 S: block-per-(b,t) kernel.
__global__ __launch_bounds__(256) void tfe_embed_bcast(
    const float* __restrict__ x, const float* __restrict__ W,
    const float* __restrict__ bias, float* __restrict__ out, int S)
{
    const int bt = blockIdx.x;
    const int tid = threadIdx.x;
    const int d4 = tid & 127;
    const int shalf = tid >> 7;
    const float4 xv = ((const float4*)x)[bt];
    const float4* Wv = (const float4*)W;
    const float4 w0 = Wv[4 * d4 + 0];
    const float4 w1 = Wv[4 * d4 + 1];
    const float4 w2 = Wv[4 * d4 + 2];
    const float4 w3 = Wv[4 * d4 + 3];
    const float4 bv = ((const float4*)bias)[d4];
    const v4f y = tfe_row(xv, w0, w1, w2, w3, bv);
    v4f* orow = (v4f*)out + (size_t)bt * (size_t)S * 128;
    for (int si = shalf; si < S; si += 2)
        __builtin_nontemporal_store(y, &orow[(size_t)si * 128 + d4]);
}

extern "C" void kernel_launch(void* const* d_in, const int* in_sizes, int n_in,
                              void* d_out, int out_size, void* d_ws, size_t ws_size,
                              hipStream_t stream) {
    const float* x    = (const float*)d_in[0];   // [B,T,4] fp32
    const float* W    = (const float*)d_in[2];   // [512,4] fp32
    const float* bias = (const float*)d_in[3];   // [512]   fp32
    float* out        = (float*)d_out;

    const int BT = in_sizes[0] / D_INP;               // 3072 (sizes in elements)
    const int S  = out_size / (BT * D_MODEL);         // 64
    const size_t N4 = (size_t)out_size / 4;           // float4 count

    if ((S & (S - 1)) == 0) {
        // btShift = log2(S * 128): S=64 -> 13
        int btShift = 0, v = S * (D_MODEL / 4);
        while ((1 << (btShift + 1)) <= v) ++btShift;

        const int G = 256, B = 256;                   // 1 block/CU, 4 waves/CU
        const size_t stride = (size_t)G * B;          // 65536 float4 = 1 MB
        const size_t row = (size_t)S * (D_MODEL / 4); // float4 per bt (8192)
        const size_t niter = (stride && N4 >= stride) ? N4 / stride : 0;

        if (niter >= 1 && niter <= 1536 &&
            (N4 % stride) == 0 &&                     // all threads run niter iters
            (stride % row) == 0 &&                    // (s,d4) invariant, btStep exact
            (row % (size_t)B) == 0) {                 // bt0 block-uniform
            tfe_flat_lds_nt<<<G, B, 0, stream>>>(
                (const float4*)x, (const float4*)W, (const float4*)bias,
                (v4f*)out, btShift, (int)niter);
        } else {
            tfe_flat<<<2048, B, 0, stream>>>(
                (const float4*)x, (const float4*)W, (const float4*)bias,
                (v4f*)out, N4, btShift);
        }
    } else {
        tfe_embed_bcast<<<BT, 256, 0, stream>>>(x, W, bias, out, S);
    }
}